// Round 3
// baseline (512.727 us; speedup 1.0000x reference)
//
#include <hip/hip_runtime.h>

// B=2,H=16,S=2048,D=128 (f32 I/O; internal bf16 MFMA)
//   qk = x1·x2^T * scale + mask;  P = softmax_k(qk);  out = x3 @ P
// Pass 1 (k_qk):  E^T[k][q] = exp(qk) (bf16, to ws), rl[q] = 1/sum_k exp
// Pass 2 (k_pv):  out = (x3 * rl) @ E      (pure bf16 GEMM, no recompute)

typedef __attribute__((ext_vector_type(8))) short short8;
typedef __attribute__((ext_vector_type(4))) float f32x4;

#define S_LEN 2048
#define D_LEN 128
#define BH_N 32
#define SCALE_QK 0.08838834764831845f

__device__ __forceinline__ unsigned short f2bf(float f) {
    union { float f; unsigned int i; } v; v.f = f;
    unsigned int r = v.i + 0x7FFFu + ((v.i >> 16) & 1u);  // RNE
    return (unsigned short)(r >> 16);
}
__device__ __forceinline__ uint2 pack4bf(float4 v) {
    uint2 p;
    p.x = (unsigned)f2bf(v.x) | ((unsigned)f2bf(v.y) << 16);
    p.y = (unsigned)f2bf(v.z) | ((unsigned)f2bf(v.w) << 16);
    return p;
}

// ---------- Kernel 1: QK -> exp -> E^T store + row sums ----------
// grid(16, 32): x = 128-row q stripe, y = bh. 256 threads (4 waves).
__global__ __launch_bounds__(256, 3) void k_qk(
    const float* __restrict__ x1,
    const float* __restrict__ x2,
    const float* __restrict__ mask,
    float* __restrict__ rl,
    unsigned short* __restrict__ ET,  // [bh][k][q] bf16 (may be null)
    int writeE)
{
    __shared__ unsigned short sQ[128 * 136];  // q x d (bf16, pre-scaled)
    __shared__ unsigned short sK[64 * 136];   // k x d (bf16)
    const int q0 = blockIdx.x * 128;
    const int bh = blockIdx.y;
    const float* x1b = x1 + (size_t)bh * S_LEN * D_LEN;
    const float* x2b = x2 + (size_t)bh * S_LEN * D_LEN;
    unsigned short* ETb = ET + (size_t)bh * S_LEN * S_LEN;
    const int t = threadIdx.x;
    const int w = t >> 6, lane = t & 63, quad = lane >> 4, l16 = lane & 15;

#pragma unroll
    for (int i = 0; i < 16; ++i) {  // stage x1*scale (128x128) f32->bf16
        int e = (i * 256 + t) * 4;
        int r = e >> 7, c = e & 127;
        float4 v = *(const float4*)&x1b[(size_t)(q0 + r) * D_LEN + c];
        v.x *= SCALE_QK; v.y *= SCALE_QK; v.z *= SCALE_QK; v.w *= SCALE_QK;
        *(uint2*)&sQ[r * 136 + c] = pack4bf(v);
    }

    float rs[8] = {0.f, 0.f, 0.f, 0.f, 0.f, 0.f, 0.f, 0.f};

    for (int k0 = 0; k0 < S_LEN; k0 += 64) {
        __syncthreads();
#pragma unroll
        for (int i = 0; i < 8; ++i) {  // stage x2 k-tile (64x128)
            int e = (i * 256 + t) * 4;
            int r = e >> 7, c = e & 127;
            float4 v = *(const float4*)&x2b[(size_t)(k0 + r) * D_LEN + c];
            *(uint2*)&sK[r * 136 + c] = pack4bf(v);
        }
        __syncthreads();

        // wave w owns q rows [32w, 32w+32); fragment-reuse ordering
        f32x4 acc[2][4];
#pragma unroll
        for (int qb = 0; qb < 2; ++qb)
#pragma unroll
            for (int kb = 0; kb < 4; ++kb) acc[qb][kb] = (f32x4){0.f, 0.f, 0.f, 0.f};
#pragma unroll
        for (int kk = 0; kk < 4; ++kk) {
            short8 a0 = *(const short8*)&sQ[(32 * w + l16) * 136 + kk * 32 + quad * 8];
            short8 a1 = *(const short8*)&sQ[(32 * w + 16 + l16) * 136 + kk * 32 + quad * 8];
            short8 b[4];
#pragma unroll
            for (int kb = 0; kb < 4; ++kb)
                b[kb] = *(const short8*)&sK[(kb * 16 + l16) * 136 + kk * 32 + quad * 8];
#pragma unroll
            for (int kb = 0; kb < 4; ++kb) {
                acc[0][kb] = __builtin_amdgcn_mfma_f32_16x16x32_bf16(a0, b[kb], acc[0][kb], 0, 0, 0);
                acc[1][kb] = __builtin_amdgcn_mfma_f32_16x16x32_bf16(a1, b[kb], acc[1][kb], 0, 0, 0);
            }
        }
        // exp + rowsum + E^T store
#pragma unroll
        for (int qb = 0; qb < 2; ++qb) {
            const int qrow = 32 * w + 16 * qb + 4 * quad;
#pragma unroll
            for (int kb = 0; kb < 4; ++kb) {
                const int kg = k0 + kb * 16 + l16;
                unsigned short e4[4];
#pragma unroll
                for (int r = 0; r < 4; ++r) {
                    float m = mask[(size_t)(q0 + qrow + r) * S_LEN + kg];
                    float ev = __expf(acc[qb][kb][r] + m);  // scale folded into A
                    rs[qb * 4 + r] += ev;
                    e4[r] = f2bf(ev);
                }
                if (writeE) {
                    uint2 pk;
                    pk.x = (unsigned)e4[0] | ((unsigned)e4[1] << 16);
                    pk.y = (unsigned)e4[2] | ((unsigned)e4[3] << 16);
                    *(uint2*)&ETb[(size_t)kg * S_LEN + q0 + qrow] = pk;
                }
            }
        }
    }
    // reduce across the 16 column-lanes; write 1/l
#pragma unroll
    for (int i = 0; i < 8; ++i) {
        float v = rs[i];
        v += __shfl_xor(v, 1);
        v += __shfl_xor(v, 2);
        v += __shfl_xor(v, 4);
        v += __shfl_xor(v, 8);
        if (l16 == 0) {
            int qg = q0 + 32 * w + 16 * (i >> 2) + 4 * quad + (i & 3);
            rl[(size_t)bh * S_LEN + qg] = 1.0f / v;
        }
    }
}

// ---------- Kernel 2: out = (x3*rl) @ E ----------
// grid(16, 32): x = 128-col k tile, y = bh. 256 threads; wave w: 32d x 128k.
__global__ __launch_bounds__(256, 2) void k_pv(
    const float* __restrict__ x3,
    const float* __restrict__ rl,
    const unsigned short* __restrict__ ET,
    float* __restrict__ out)
{
    __shared__ unsigned short sX[128 * 72];  // d x q (bf16, rl-scaled)
    __shared__ unsigned short sE[128 * 72];  // k x q (bf16)
    const int k0 = blockIdx.x * 128;
    const int bh = blockIdx.y;
    const float* x3b = x3 + (size_t)bh * (size_t)D_LEN * S_LEN;
    const float* rlb = rl + (size_t)bh * S_LEN;
    const unsigned short* ETb = ET + (size_t)bh * S_LEN * S_LEN;
    const int t = threadIdx.x;
    const int w = t >> 6, lane = t & 63, quad = lane >> 4, l16 = lane & 15;

    f32x4 oa[16];  // 2 db x 8 kb
#pragma unroll
    for (int i = 0; i < 16; ++i) oa[i] = (f32x4){0.f, 0.f, 0.f, 0.f};

    for (int q0 = 0; q0 < S_LEN; q0 += 64) {
        __syncthreads();
#pragma unroll
        for (int i = 0; i < 8; ++i) {  // stage x3 (128d x 64q), scale by rl
            int e = (i * 256 + t) * 4;
            int r = e >> 6, c = e & 63;
            float4 v = *(const float4*)&x3b[(size_t)r * S_LEN + q0 + c];
            float4 s = *(const float4*)&rlb[q0 + c];
            v.x *= s.x; v.y *= s.y; v.z *= s.z; v.w *= s.w;
            *(uint2*)&sX[r * 72 + c] = pack4bf(v);
        }
#pragma unroll
        for (int i = 0; i < 4; ++i) {  // stage E^T (128k x 64q), straight copy
            int e = (i * 256 + t) * 8;
            int r = e >> 6, c = e & 63;
            *(uint4*)&sE[r * 72 + c] = *(const uint4*)&ETb[(size_t)(k0 + r) * S_LEN + q0 + c];
        }
        __syncthreads();

#pragma unroll
        for (int kk = 0; kk < 2; ++kk) {
            short8 a[2];
#pragma unroll
            for (int db = 0; db < 2; ++db)
                a[db] = *(const short8*)&sX[(32 * w + 16 * db + l16) * 72 + kk * 32 + quad * 8];
            short8 b[8];
#pragma unroll
            for (int kb = 0; kb < 8; ++kb)
                b[kb] = *(const short8*)&sE[(kb * 16 + l16) * 72 + kk * 32 + quad * 8];
#pragma unroll
            for (int db = 0; db < 2; ++db)
#pragma unroll
                for (int kb = 0; kb < 8; ++kb)
                    oa[db * 8 + kb] = __builtin_amdgcn_mfma_f32_16x16x32_bf16(a[db], b[kb], oa[db * 8 + kb], 0, 0, 0);
        }
    }

#pragma unroll
    for (int db = 0; db < 2; ++db)
#pragma unroll
        for (int kb = 0; kb < 8; ++kb)
#pragma unroll
            for (int r = 0; r < 4; ++r) {
                int d = 32 * w + 16 * db + 4 * quad + r;
                out[((size_t)bh * D_LEN + d) * S_LEN + k0 + kb * 16 + l16] =
                    oa[db * 8 + kb][r];
            }
}

// ---------- Fallback (ws too small): round-2 recompute K2 ----------
__global__ __launch_bounds__(256, 2) void k_out_fb(
    const float* __restrict__ x1,
    const float* __restrict__ x2,
    const float* __restrict__ x3,
    const float* __restrict__ mask,
    const float* __restrict__ rl,
    float* __restrict__ out)
{
    __shared__ unsigned short sK[64 * 136];
    __shared__ unsigned short sQ[64 * 136];
    __shared__ unsigned short sX[128 * 72];
    __shared__ unsigned short sE[64 * 72];
    const int kb0 = blockIdx.x * 64;
    const int bh = blockIdx.y;
    const float* x1b = x1 + (size_t)bh * S_LEN * D_LEN;
    const float* x2b = x2 + (size_t)bh * S_LEN * D_LEN;
    const float* x3b = x3 + (size_t)bh * (size_t)D_LEN * S_LEN;
    const float* rlb = rl + (size_t)bh * S_LEN;
    const int t = threadIdx.x;
    const int w = t >> 6, lane = t & 63, quad = lane >> 4, l16 = lane & 15;

#pragma unroll
    for (int i = 0; i < 8; ++i) {
        int e = (i * 256 + t) * 4;
        int r = e >> 7, c = e & 127;
        float4 v = *(const float4*)&x2b[(size_t)(kb0 + r) * D_LEN + c];
        *(uint2*)&sK[r * 136 + c] = pack4bf(v);
    }
    f32x4 oa[8];
#pragma unroll
    for (int i = 0; i < 8; ++i) oa[i] = (f32x4){0.f, 0.f, 0.f, 0.f};

    for (int q0 = 0; q0 < S_LEN; q0 += 64) {
        __syncthreads();
#pragma unroll
        for (int i = 0; i < 8; ++i) {
            int e = (i * 256 + t) * 4;
            int r = e >> 7, c = e & 127;
            float4 v = *(const float4*)&x1b[(size_t)(q0 + r) * D_LEN + c];
            *(uint2*)&sQ[r * 136 + c] = pack4bf(v);
        }
#pragma unroll
        for (int i = 0; i < 8; ++i) {
            int e = (i * 256 + t) * 4;
            int r = e >> 6, c = e & 63;
            float4 v = *(const float4*)&x3b[(size_t)r * S_LEN + q0 + c];
            *(uint2*)&sX[r * 72 + c] = pack4bf(v);
        }
        __syncthreads();
        const int qrow = 16 * w + 4 * quad;
        float rl4[4];
#pragma unroll
        for (int r = 0; r < 4; ++r) rl4[r] = rlb[q0 + qrow + r];
#pragma unroll
        for (int kb = 0; kb < 4; ++kb) {
            f32x4 acc = {0.f, 0.f, 0.f, 0.f};
#pragma unroll
            for (int kk = 0; kk < 4; ++kk) {
                short8 a = *(const short8*)&sQ[(16 * w + l16) * 136 + kk * 32 + quad * 8];
                short8 b = *(const short8*)&sK[(kb * 16 + l16) * 136 + kk * 32 + quad * 8];
                acc = __builtin_amdgcn_mfma_f32_16x16x32_bf16(a, b, acc, 0, 0, 0);
            }
            const int kg = kb0 + kb * 16 + l16;
            unsigned short e4[4];
#pragma unroll
            for (int r = 0; r < 4; ++r) {
                float m = mask[(size_t)(q0 + qrow + r) * S_LEN + kg];
                e4[r] = f2bf(__expf(acc[r] * SCALE_QK + m) * rl4[r]);
            }
            uint2 pk;
            pk.x = (unsigned)e4[0] | ((unsigned)e4[1] << 16);
            pk.y = (unsigned)e4[2] | ((unsigned)e4[3] << 16);
            *(uint2*)&sE[(kb * 16 + l16) * 72 + qrow] = pk;
        }
        __syncthreads();
#pragma unroll
        for (int db = 0; db < 2; ++db)
#pragma unroll
            for (int kb = 0; kb < 4; ++kb) {
                f32x4 a0 = oa[db * 4 + kb];
#pragma unroll
                for (int kk = 0; kk < 2; ++kk) {
                    short8 a = *(const short8*)&sX[(32 * w + 16 * db + l16) * 72 + kk * 32 + quad * 8];
                    short8 b = *(const short8*)&sE[(kb * 16 + l16) * 72 + kk * 32 + quad * 8];
                    a0 = __builtin_amdgcn_mfma_f32_16x16x32_bf16(a, b, a0, 0, 0, 0);
                }
                oa[db * 4 + kb] = a0;
            }
    }
#pragma unroll
    for (int db = 0; db < 2; ++db)
#pragma unroll
        for (int kb = 0; kb < 4; ++kb)
#pragma unroll
            for (int r = 0; r < 4; ++r) {
                int d = 32 * w + 16 * db + 4 * quad + r;
                out[((size_t)bh * D_LEN + d) * S_LEN + kb0 + kb * 16 + l16] =
                    oa[db * 4 + kb][r];
            }
}

extern "C" void kernel_launch(void* const* d_in, const int* in_sizes, int n_in,
                              void* d_out, int out_size, void* d_ws, size_t ws_size,
                              hipStream_t stream) {
    const float* x1 = (const float*)d_in[0];
    const float* x2 = (const float*)d_in[1];
    const float* x3 = (const float*)d_in[2];
    const float* mask = (const float*)d_in[3];
    float* out = (float*)d_out;

    const size_t rl_bytes = (size_t)BH_N * S_LEN * sizeof(float);            // 256 KB
    const size_t e_bytes = (size_t)BH_N * S_LEN * S_LEN * sizeof(unsigned short);  // 256 MB
    float* rl = (float*)d_ws;

    if (ws_size >= rl_bytes + e_bytes) {
        unsigned short* ET = (unsigned short*)((char*)d_ws + rl_bytes);
        k_qk<<<dim3(S_LEN / 128, BH_N), dim3(256), 0, stream>>>(x1, x2, mask, rl, ET, 1);
        k_pv<<<dim3(S_LEN / 128, BH_N), dim3(256), 0, stream>>>(x3, rl, ET, out);
    } else {
        k_qk<<<dim3(S_LEN / 128, BH_N), dim3(256), 0, stream>>>(x1, x2, mask, rl, (unsigned short*)nullptr, 0);
        k_out_fb<<<dim3(S_LEN / 64, BH_N), dim3(256), 0, stream>>>(x1, x2, x3, mask, rl, out);
    }
}

// Round 4
// 347.239 us; speedup vs baseline: 1.4766x; 1.4766x over previous
//
#include <hip/hip_runtime.h>

// B=2,H=16,S=2048,D=128 (f32 I/O; internal bf16 MFMA)
//   qk = x1·x2^T*scale + mask;  P = softmax_k(qk);  out = x3 @ P
// ws (58.7 MB): x1s = bf16(x1*scale), x2b = bf16(x2), x3s = bf16(x3*rl),
//               mbf = bf16(mask)
//   k_cvt: one-time conversions (x1s, x2b, mbf)
//   k_qk : rowsums rl (LDS-local) + writes x3s stripe (rl folded in)
//   k_out: recompute QK from bf16, exp(+mask), PV with pre-scaled x3s

typedef __attribute__((ext_vector_type(8))) short short8;
typedef __attribute__((ext_vector_type(4))) float f32x4;

#define S_LEN 2048
#define D_LEN 128
#define BH_N 32
#define SCALE_QK 0.08838834764831845f

__device__ __forceinline__ unsigned short f2bf(float f) {
    union { float f; unsigned int i; } v; v.f = f;
    unsigned int r = v.i + 0x7FFFu + ((v.i >> 16) & 1u);  // RNE
    return (unsigned short)(r >> 16);
}
__device__ __forceinline__ float bf2f(unsigned short u) {
    union { unsigned int i; float f; } v; v.i = ((unsigned int)u) << 16; return v.f;
}
__device__ __forceinline__ uint2 pack4bf(float4 v) {
    uint2 p;
    p.x = (unsigned)f2bf(v.x) | ((unsigned)f2bf(v.y) << 16);
    p.y = (unsigned)f2bf(v.z) | ((unsigned)f2bf(v.w) << 16);
    return p;
}

// ---------- Kernel 0: one-time f32 -> bf16 conversions ----------
// covers x1 (scaled), x2, mask. 1 float4 per thread, exact grid.
__global__ void k_cvt(const float* __restrict__ x1,
                      const float* __restrict__ x2,
                      const float* __restrict__ mask,
                      unsigned short* __restrict__ x1s,
                      unsigned short* __restrict__ x2b,
                      unsigned short* __restrict__ mbf) {
    const size_t N1 = (size_t)BH_N * S_LEN * D_LEN;      // 8.39M
    const size_t NM = (size_t)S_LEN * S_LEN;             // 4.19M
    size_t i = ((size_t)blockIdx.x * 256 + threadIdx.x) * 4;
    if (i < N1) {
        float4 v = *(const float4*)&x1[i];
        v.x *= SCALE_QK; v.y *= SCALE_QK; v.z *= SCALE_QK; v.w *= SCALE_QK;
        *(uint2*)&x1s[i] = pack4bf(v);
    } else if (i < 2 * N1) {
        size_t j = i - N1;
        float4 v = *(const float4*)&x2[j];
        *(uint2*)&x2b[j] = pack4bf(v);
    } else if (i < 2 * N1 + NM) {
        size_t j = i - 2 * N1;
        float4 v = *(const float4*)&mask[j];
        *(uint2*)&mbf[j] = pack4bf(v);
    }
}

// ---------- Kernel 1: rowsums + x3s stripe conversion ----------
// grid(16, 32): x = 128-row q stripe, y = bh. 256 threads (4 waves).
__global__ __launch_bounds__(256, 3) void k_qk(
    const unsigned short* __restrict__ x1s,
    const unsigned short* __restrict__ x2b,
    const unsigned short* __restrict__ mbf,
    const float* __restrict__ x3,
    unsigned short* __restrict__ x3s)
{
    __shared__ unsigned short sQ[128 * 136];  // q x d bf16 (pre-scaled)
    __shared__ unsigned short sK[64 * 136];   // k x d bf16
    __shared__ float sRL[128];
    const int q0 = blockIdx.x * 128;
    const int bh = blockIdx.y;
    const unsigned short* x1p = x1s + (size_t)bh * S_LEN * D_LEN;
    const unsigned short* x2p = x2b + (size_t)bh * S_LEN * D_LEN;
    const int t = threadIdx.x;
    const int w = t >> 6, lane = t & 63, quad = lane >> 4, l16 = lane & 15;

#pragma unroll
    for (int i = 0; i < 8; ++i) {  // stage sQ (128x128 bf16) pure copy
        int e = (i * 256 + t) * 8;
        int r = e >> 7, c = e & 127;
        *(uint4*)&sQ[r * 136 + c] = *(const uint4*)&x1p[(size_t)(q0 + r) * D_LEN + c];
    }

    float rs[8] = {0.f, 0.f, 0.f, 0.f, 0.f, 0.f, 0.f, 0.f};

    for (int k0 = 0; k0 < S_LEN; k0 += 64) {
        __syncthreads();
#pragma unroll
        for (int i = 0; i < 4; ++i) {  // stage sK (64x128 bf16) pure copy
            int e = (i * 256 + t) * 8;
            int r = e >> 7, c = e & 127;
            *(uint4*)&sK[r * 136 + c] = *(const uint4*)&x2p[(size_t)(k0 + r) * D_LEN + c];
        }
        __syncthreads();

        f32x4 acc[2][4];
#pragma unroll
        for (int qb = 0; qb < 2; ++qb)
#pragma unroll
            for (int kb = 0; kb < 4; ++kb) acc[qb][kb] = (f32x4){0.f, 0.f, 0.f, 0.f};
#pragma unroll
        for (int kk = 0; kk < 4; ++kk) {
            short8 a0 = *(const short8*)&sQ[(32 * w + l16) * 136 + kk * 32 + quad * 8];
            short8 a1 = *(const short8*)&sQ[(32 * w + 16 + l16) * 136 + kk * 32 + quad * 8];
            short8 b[4];
#pragma unroll
            for (int kb = 0; kb < 4; ++kb)
                b[kb] = *(const short8*)&sK[(kb * 16 + l16) * 136 + kk * 32 + quad * 8];
#pragma unroll
            for (int kb = 0; kb < 4; ++kb) {
                acc[0][kb] = __builtin_amdgcn_mfma_f32_16x16x32_bf16(a0, b[kb], acc[0][kb], 0, 0, 0);
                acc[1][kb] = __builtin_amdgcn_mfma_f32_16x16x32_bf16(a1, b[kb], acc[1][kb], 0, 0, 0);
            }
        }
#pragma unroll
        for (int qb = 0; qb < 2; ++qb) {
            const int qrow = 32 * w + 16 * qb + 4 * quad;
#pragma unroll
            for (int kb = 0; kb < 4; ++kb) {
                const int kg = k0 + kb * 16 + l16;
#pragma unroll
                for (int r = 0; r < 4; ++r) {
                    float m = bf2f(mbf[(size_t)(q0 + qrow + r) * S_LEN + kg]);
                    rs[qb * 4 + r] += __expf(acc[qb][kb][r] + m);
                }
            }
        }
    }
    // reduce across 16 column-lanes; rl -> LDS
#pragma unroll
    for (int i = 0; i < 8; ++i) {
        float v = rs[i];
        v += __shfl_xor(v, 1);
        v += __shfl_xor(v, 2);
        v += __shfl_xor(v, 4);
        v += __shfl_xor(v, 8);
        if (l16 == 0) sRL[32 * w + 16 * (i >> 2) + 4 * quad + (i & 3)] = 1.0f / v;
    }
    __syncthreads();

    // x3s[:, q0:q0+128] = bf16(x3 * rl) for this bh
    const float* x3b = x3 + (size_t)bh * (size_t)D_LEN * S_LEN;
    unsigned short* x3sp = x3s + (size_t)bh * (size_t)D_LEN * S_LEN;
#pragma unroll
    for (int i = 0; i < 16; ++i) {
        int e = (i * 256 + t) * 4;
        int r = e >> 7, c = e & 127;
        float4 v = *(const float4*)&x3b[(size_t)r * S_LEN + q0 + c];
        v.x *= sRL[c]; v.y *= sRL[c + 1]; v.z *= sRL[c + 2]; v.w *= sRL[c + 3];
        *(uint2*)&x3sp[(size_t)r * S_LEN + q0 + c] = pack4bf(v);
    }
}

// ---------- Kernel 2: out = x3s @ exp(QK + mask) ----------
// grid(32, 32): x = 64-col k block, y = bh. 256 threads (4 waves).
__global__ __launch_bounds__(256, 2) void k_out(
    const unsigned short* __restrict__ x1s,
    const unsigned short* __restrict__ x2b,
    const unsigned short* __restrict__ x3s,
    const unsigned short* __restrict__ mbf,
    float* __restrict__ out)
{
    __shared__ unsigned short sK[64 * 136];  // x2 k-block, resident
    __shared__ unsigned short sQ[64 * 136];  // x1 q-tile
    __shared__ unsigned short sX[128 * 72];  // x3s tile (d x q)
    __shared__ unsigned short sE[64 * 72];   // E^T (k x q)
    const int kb0 = blockIdx.x * 64;
    const int bh = blockIdx.y;
    const unsigned short* x1p = x1s + (size_t)bh * S_LEN * D_LEN;
    const unsigned short* x2p = x2b + (size_t)bh * S_LEN * D_LEN;
    const unsigned short* x3p = x3s + (size_t)bh * (size_t)D_LEN * S_LEN;
    const int t = threadIdx.x;
    const int w = t >> 6, lane = t & 63, quad = lane >> 4, l16 = lane & 15;

#pragma unroll
    for (int i = 0; i < 4; ++i) {  // resident x2 k-block (64x128) pure copy
        int e = (i * 256 + t) * 8;
        int r = e >> 7, c = e & 127;
        *(uint4*)&sK[r * 136 + c] = *(const uint4*)&x2p[(size_t)(kb0 + r) * D_LEN + c];
    }

    f32x4 oa[8];
#pragma unroll
    for (int i = 0; i < 8; ++i) oa[i] = (f32x4){0.f, 0.f, 0.f, 0.f};

    for (int q0 = 0; q0 < S_LEN; q0 += 64) {
        __syncthreads();
#pragma unroll
        for (int i = 0; i < 4; ++i) {  // stage x1 q-tile (64x128) pure copy
            int e = (i * 256 + t) * 8;
            int r = e >> 7, c = e & 127;
            *(uint4*)&sQ[r * 136 + c] = *(const uint4*)&x1p[(size_t)(q0 + r) * D_LEN + c];
        }
#pragma unroll
        for (int i = 0; i < 4; ++i) {  // stage x3s tile (128d x 64q) pure copy
            int e = (i * 256 + t) * 8;
            int r = e >> 6, c = e & 63;
            *(uint4*)&sX[r * 72 + c] = *(const uint4*)&x3p[(size_t)r * S_LEN + q0 + c];
        }
        __syncthreads();

        // QK: wave w owns q rows [16w, 16w+16); kk-outer fragment reuse
        f32x4 acc[4];
#pragma unroll
        for (int kb = 0; kb < 4; ++kb) acc[kb] = (f32x4){0.f, 0.f, 0.f, 0.f};
#pragma unroll
        for (int kk = 0; kk < 4; ++kk) {
            short8 a = *(const short8*)&sQ[(16 * w + l16) * 136 + kk * 32 + quad * 8];
            short8 b[4];
#pragma unroll
            for (int kb = 0; kb < 4; ++kb)
                b[kb] = *(const short8*)&sK[(kb * 16 + l16) * 136 + kk * 32 + quad * 8];
#pragma unroll
            for (int kb = 0; kb < 4; ++kb)
                acc[kb] = __builtin_amdgcn_mfma_f32_16x16x32_bf16(a, b[kb], acc[kb], 0, 0, 0);
        }
        const int qrow = 16 * w + 4 * quad;
#pragma unroll
        for (int kb = 0; kb < 4; ++kb) {
            const int kg = kb0 + kb * 16 + l16;
            unsigned short e4[4];
#pragma unroll
            for (int r = 0; r < 4; ++r) {
                float m = bf2f(mbf[(size_t)(q0 + qrow + r) * S_LEN + kg]);
                e4[r] = f2bf(__expf(acc[kb][r] + m));
            }
            uint2 pk;
            pk.x = (unsigned)e4[0] | ((unsigned)e4[1] << 16);
            pk.y = (unsigned)e4[2] | ((unsigned)e4[3] << 16);
            *(uint2*)&sE[(kb * 16 + l16) * 72 + qrow] = pk;
        }
        __syncthreads();

        // PV: wave w owns d rows [32w, 32w+32)
#pragma unroll
        for (int kk = 0; kk < 2; ++kk) {
            short8 a[2];
#pragma unroll
            for (int db = 0; db < 2; ++db)
                a[db] = *(const short8*)&sX[(32 * w + 16 * db + l16) * 72 + kk * 32 + quad * 8];
            short8 b[4];
#pragma unroll
            for (int kb = 0; kb < 4; ++kb)
                b[kb] = *(const short8*)&sE[(kb * 16 + l16) * 72 + kk * 32 + quad * 8];
#pragma unroll
            for (int db = 0; db < 2; ++db)
#pragma unroll
                for (int kb = 0; kb < 4; ++kb)
                    oa[db * 4 + kb] = __builtin_amdgcn_mfma_f32_16x16x32_bf16(a[db], b[kb], oa[db * 4 + kb], 0, 0, 0);
        }
    }

#pragma unroll
    for (int db = 0; db < 2; ++db)
#pragma unroll
        for (int kb = 0; kb < 4; ++kb)
#pragma unroll
            for (int r = 0; r < 4; ++r) {
                int d = 32 * w + 16 * db + 4 * quad + r;
                out[((size_t)bh * D_LEN + d) * S_LEN + kb0 + kb * 16 + l16] =
                    oa[db * 4 + kb][r];
            }
}

// ================= Fallback path (ws too small): round-2 kernels =========
__global__ __launch_bounds__(256, 3) void k_rowsum_fb(
    const float* __restrict__ x1, const float* __restrict__ x2,
    const float* __restrict__ mask, float* __restrict__ rl)
{
    __shared__ unsigned short sQ[128 * 136];
    __shared__ unsigned short sK[64 * 136];
    const int q0 = blockIdx.x * 128;
    const int bh = blockIdx.y;
    const float* x1b = x1 + (size_t)bh * S_LEN * D_LEN;
    const float* x2b = x2 + (size_t)bh * S_LEN * D_LEN;
    const int t = threadIdx.x;
    const int w = t >> 6, lane = t & 63, quad = lane >> 4, l16 = lane & 15;
#pragma unroll
    for (int i = 0; i < 16; ++i) {
        int e = (i * 256 + t) * 4;
        int r = e >> 7, c = e & 127;
        float4 v = *(const float4*)&x1b[(size_t)(q0 + r) * D_LEN + c];
        *(uint2*)&sQ[r * 136 + c] = pack4bf(v);
    }
    float rs[8] = {0.f, 0.f, 0.f, 0.f, 0.f, 0.f, 0.f, 0.f};
    for (int k0 = 0; k0 < S_LEN; k0 += 64) {
        __syncthreads();
#pragma unroll
        for (int i = 0; i < 8; ++i) {
            int e = (i * 256 + t) * 4;
            int r = e >> 7, c = e & 127;
            float4 v = *(const float4*)&x2b[(size_t)(k0 + r) * D_LEN + c];
            *(uint2*)&sK[r * 136 + c] = pack4bf(v);
        }
        __syncthreads();
#pragma unroll
        for (int qb = 0; qb < 2; ++qb) {
            const int qrow = 32 * w + 16 * qb;
#pragma unroll
            for (int kb = 0; kb < 4; ++kb) {
                f32x4 acc = {0.f, 0.f, 0.f, 0.f};
#pragma unroll
                for (int kk = 0; kk < 4; ++kk) {
                    short8 a = *(const short8*)&sQ[(qrow + l16) * 136 + kk * 32 + quad * 8];
                    short8 b = *(const short8*)&sK[(kb * 16 + l16) * 136 + kk * 32 + quad * 8];
                    acc = __builtin_amdgcn_mfma_f32_16x16x32_bf16(a, b, acc, 0, 0, 0);
                }
                const int kg = k0 + kb * 16 + l16;
                const int qg = q0 + qrow + 4 * quad;
#pragma unroll
                for (int r = 0; r < 4; ++r) {
                    float m = mask[(size_t)(qg + r) * S_LEN + kg];
                    rs[qb * 4 + r] += __expf(acc[r] * SCALE_QK + m);
                }
            }
        }
    }
#pragma unroll
    for (int i = 0; i < 8; ++i) {
        float v = rs[i];
        v += __shfl_xor(v, 1); v += __shfl_xor(v, 2);
        v += __shfl_xor(v, 4); v += __shfl_xor(v, 8);
        if (l16 == 0) {
            int qg = q0 + 32 * w + 16 * (i >> 2) + 4 * quad + (i & 3);
            rl[(size_t)bh * S_LEN + qg] = 1.0f / v;
        }
    }
}

__global__ __launch_bounds__(256, 2) void k_out_fb(
    const float* __restrict__ x1, const float* __restrict__ x2,
    const float* __restrict__ x3, const float* __restrict__ mask,
    const float* __restrict__ rl, float* __restrict__ out)
{
    __shared__ unsigned short sK[64 * 136];
    __shared__ unsigned short sQ[64 * 136];
    __shared__ unsigned short sX[128 * 72];
    __shared__ unsigned short sE[64 * 72];
    const int kb0 = blockIdx.x * 64;
    const int bh = blockIdx.y;
    const float* x1b = x1 + (size_t)bh * S_LEN * D_LEN;
    const float* x2b = x2 + (size_t)bh * S_LEN * D_LEN;
    const float* x3b = x3 + (size_t)bh * (size_t)D_LEN * S_LEN;
    const float* rlb = rl + (size_t)bh * S_LEN;
    const int t = threadIdx.x;
    const int w = t >> 6, lane = t & 63, quad = lane >> 4, l16 = lane & 15;
#pragma unroll
    for (int i = 0; i < 8; ++i) {
        int e = (i * 256 + t) * 4;
        int r = e >> 7, c = e & 127;
        float4 v = *(const float4*)&x2b[(size_t)(kb0 + r) * D_LEN + c];
        *(uint2*)&sK[r * 136 + c] = pack4bf(v);
    }
    f32x4 oa[8];
#pragma unroll
    for (int i = 0; i < 8; ++i) oa[i] = (f32x4){0.f, 0.f, 0.f, 0.f};
    for (int q0 = 0; q0 < S_LEN; q0 += 64) {
        __syncthreads();
#pragma unroll
        for (int i = 0; i < 8; ++i) {
            int e = (i * 256 + t) * 4;
            int r = e >> 7, c = e & 127;
            float4 v = *(const float4*)&x1b[(size_t)(q0 + r) * D_LEN + c];
            *(uint2*)&sQ[r * 136 + c] = pack4bf(v);
        }
#pragma unroll
        for (int i = 0; i < 8; ++i) {
            int e = (i * 256 + t) * 4;
            int r = e >> 6, c = e & 63;
            float4 v = *(const float4*)&x3b[(size_t)r * S_LEN + q0 + c];
            *(uint2*)&sX[r * 72 + c] = pack4bf(v);
        }
        __syncthreads();
        const int qrow = 16 * w + 4 * quad;
        float rl4[4];
#pragma unroll
        for (int r = 0; r < 4; ++r) rl4[r] = rlb[q0 + qrow + r];
#pragma unroll
        for (int kb = 0; kb < 4; ++kb) {
            f32x4 acc = {0.f, 0.f, 0.f, 0.f};
#pragma unroll
            for (int kk = 0; kk < 4; ++kk) {
                short8 a = *(const short8*)&sQ[(16 * w + l16) * 136 + kk * 32 + quad * 8];
                short8 b = *(const short8*)&sK[(kb * 16 + l16) * 136 + kk * 32 + quad * 8];
                acc = __builtin_amdgcn_mfma_f32_16x16x32_bf16(a, b, acc, 0, 0, 0);
            }
            const int kg = kb0 + kb * 16 + l16;
            unsigned short e4[4];
#pragma unroll
            for (int r = 0; r < 4; ++r) {
                float m = mask[(size_t)(q0 + qrow + r) * S_LEN + kg];
                e4[r] = f2bf(__expf(acc[r] * SCALE_QK + m) * rl4[r]);
            }
            uint2 pk;
            pk.x = (unsigned)e4[0] | ((unsigned)e4[1] << 16);
            pk.y = (unsigned)e4[2] | ((unsigned)e4[3] << 16);
            *(uint2*)&sE[(kb * 16 + l16) * 72 + qrow] = pk;
        }
        __syncthreads();
#pragma unroll
        for (int db = 0; db < 2; ++db)
#pragma unroll
            for (int kb = 0; kb < 4; ++kb) {
                f32x4 a0 = oa[db * 4 + kb];
#pragma unroll
                for (int kk = 0; kk < 2; ++kk) {
                    short8 a = *(const short8*)&sX[(32 * w + 16 * db + l16) * 72 + kk * 32 + quad * 8];
                    short8 b = *(const short8*)&sE[(kb * 16 + l16) * 72 + kk * 32 + quad * 8];
                    a0 = __builtin_amdgcn_mfma_f32_16x16x32_bf16(a, b, a0, 0, 0, 0);
                }
                oa[db * 4 + kb] = a0;
            }
    }
#pragma unroll
    for (int db = 0; db < 2; ++db)
#pragma unroll
        for (int kb = 0; kb < 4; ++kb)
#pragma unroll
            for (int r = 0; r < 4; ++r) {
                int d = 32 * w + 16 * db + 4 * quad + r;
                out[((size_t)bh * D_LEN + d) * S_LEN + kb0 + kb * 16 + l16] =
                    oa[db * 4 + kb][r];
            }
}

extern "C" void kernel_launch(void* const* d_in, const int* in_sizes, int n_in,
                              void* d_out, int out_size, void* d_ws, size_t ws_size,
                              hipStream_t stream) {
    const float* x1 = (const float*)d_in[0];
    const float* x2 = (const float*)d_in[1];
    const float* x3 = (const float*)d_in[2];
    const float* mask = (const float*)d_in[3];
    float* out = (float*)d_out;

    const size_t N1 = (size_t)BH_N * S_LEN * D_LEN;          // 8,388,608
    const size_t NM = (size_t)S_LEN * S_LEN;                 // 4,194,304
    const size_t need = (3 * N1 + NM) * sizeof(unsigned short);  // 58.7 MB

    if (ws_size >= need) {
        unsigned short* x1s = (unsigned short*)d_ws;
        unsigned short* x2b = x1s + N1;
        unsigned short* x3s = x2b + N1;
        unsigned short* mbf = x3s + N1;
        const size_t tot4 = (2 * N1 + NM) / 4;               // 5,242,880
        k_cvt<<<dim3((unsigned)(tot4 / 256)), dim3(256), 0, stream>>>(x1, x2, mask, x1s, x2b, mbf);
        k_qk<<<dim3(S_LEN / 128, BH_N), dim3(256), 0, stream>>>(x1s, x2b, mbf, x3, x3s);
        k_out<<<dim3(S_LEN / 64, BH_N), dim3(256), 0, stream>>>(x1s, x2b, x3s, mbf, out);
    } else {
        float* rl = (float*)d_ws;  // 256 KB
        k_rowsum_fb<<<dim3(S_LEN / 128, BH_N), dim3(256), 0, stream>>>(x1, x2, mask, rl);
        k_out_fb<<<dim3(S_LEN / 64, BH_N), dim3(256), 0, stream>>>(x1, x2, x3, mask, rl, out);
    }
}

// Round 5
// 332.760 us; speedup vs baseline: 1.5408x; 1.0435x over previous
//
#include <hip/hip_runtime.h>

// B=2,H=16,S=2048,D=128 (f32 I/O; internal bf16 MFMA)
//   qk = x1·x2^T*scale + mask;  P = softmax_k(qk);  out = x3 @ P
// ws (58.7 MB): x1s=bf16(x1*scale), x2b=bf16(x2), x3s=bf16(x3*rl), mbf=bf16(mask)
//   k_cvt: one-time conversions
//   k_qk : rowsums (swapped MFMA: A=x2 so C rows = k -> uint2 mask loads),
//          writes x3s stripe with rl folded in
//   k_out: 128-k block; QK recompute + exp + PV, XOR-swizzled LDS (no pads)
// LDS swizzle: 16B chunk c of row r stored at (c ^ (r&7)) -> bank-uniform for
// both row-staging writes and column-pattern fragment reads.

typedef __attribute__((ext_vector_type(8))) short short8;
typedef __attribute__((ext_vector_type(4))) float f32x4;

#define S_LEN 2048
#define D_LEN 128
#define BH_N 32
#define SCALE_QK 0.08838834764831845f

__device__ __forceinline__ unsigned short f2bf(float f) {
    union { float f; unsigned int i; } v; v.f = f;
    unsigned int r = v.i + 0x7FFFu + ((v.i >> 16) & 1u);  // RNE
    return (unsigned short)(r >> 16);
}
__device__ __forceinline__ float bf2f(unsigned short u) {
    union { unsigned int i; float f; } v; v.i = ((unsigned int)u) << 16; return v.f;
}
__device__ __forceinline__ uint2 pack4bf(float4 v) {
    uint2 p;
    p.x = (unsigned)f2bf(v.x) | ((unsigned)f2bf(v.y) << 16);
    p.y = (unsigned)f2bf(v.z) | ((unsigned)f2bf(v.w) << 16);
    return p;
}

// ---------- Kernel 0: one-time f32 -> bf16 conversions ----------
__global__ void k_cvt(const float* __restrict__ x1,
                      const float* __restrict__ x2,
                      const float* __restrict__ mask,
                      unsigned short* __restrict__ x1s,
                      unsigned short* __restrict__ x2b,
                      unsigned short* __restrict__ mbf) {
    const size_t N1 = (size_t)BH_N * S_LEN * D_LEN;
    const size_t NM = (size_t)S_LEN * S_LEN;
    size_t i = ((size_t)blockIdx.x * 256 + threadIdx.x) * 4;
    if (i < N1) {
        float4 v = *(const float4*)&x1[i];
        v.x *= SCALE_QK; v.y *= SCALE_QK; v.z *= SCALE_QK; v.w *= SCALE_QK;
        *(uint2*)&x1s[i] = pack4bf(v);
    } else if (i < 2 * N1) {
        size_t j = i - N1;
        float4 v = *(const float4*)&x2[j];
        *(uint2*)&x2b[j] = pack4bf(v);
    } else if (i < 2 * N1 + NM) {
        size_t j = i - 2 * N1;
        float4 v = *(const float4*)&mask[j];
        *(uint2*)&mbf[j] = pack4bf(v);
    }
}

// ---------- Kernel 1: rowsums (A=x2 swap) + x3s stripe ----------
// grid(16, 32): x = 128-col q stripe, y = bh. 4 waves.
// scores C[k][q]; wave w owns k rows [32w,32w+32) of each 128-k tile.
__global__ __launch_bounds__(256, 2) void k_qk(
    const unsigned short* __restrict__ x1s,
    const unsigned short* __restrict__ x2b,
    const unsigned short* __restrict__ mbf,
    const float* __restrict__ x3,
    unsigned short* __restrict__ x3s)
{
    __shared__ unsigned short sQ[128 * 128];  // q x d bf16 (resident, swizzled)
    __shared__ unsigned short sK[128 * 128];  // k x d bf16 (per-iter, swizzled)
    __shared__ float sRSp[4][128];
    __shared__ float sRL[128];
    const int q0 = blockIdx.x * 128;
    const int bh = blockIdx.y;
    const unsigned short* x1p = x1s + (size_t)bh * S_LEN * D_LEN;
    const unsigned short* x2p = x2b + (size_t)bh * S_LEN * D_LEN;
    const int t = threadIdx.x;
    const int w = t >> 6, lane = t & 63, quad = lane >> 4, l16 = lane & 15;

#pragma unroll
    for (int i = 0; i < 8; ++i) {  // stage resident sQ (128x128), swizzled
        int idx = i * 256 + t;
        int r = idx >> 4, c = idx & 15;
        *(uint4*)&sQ[r * 128 + ((c ^ (r & 7)) * 8)] =
            *(const uint4*)&x1p[(size_t)(q0 + r) * D_LEN + c * 8];
    }

    float rs[8] = {0.f, 0.f, 0.f, 0.f, 0.f, 0.f, 0.f, 0.f};

    for (int k0 = 0; k0 < S_LEN; k0 += 128) {
        __syncthreads();
#pragma unroll
        for (int i = 0; i < 8; ++i) {  // stage sK (128x128), swizzled
            int idx = i * 256 + t;
            int r = idx >> 4, c = idx & 15;
            *(uint4*)&sK[r * 128 + ((c ^ (r & 7)) * 8)] =
                *(const uint4*)&x2p[(size_t)(k0 + r) * D_LEN + c * 8];
        }
        __syncthreads();

        f32x4 acc[2][8];
#pragma unroll
        for (int kb = 0; kb < 2; ++kb)
#pragma unroll
            for (int qt = 0; qt < 8; ++qt) acc[kb][qt] = (f32x4){0.f, 0.f, 0.f, 0.f};
#pragma unroll
        for (int kk = 0; kk < 4; ++kk) {
            const int sc = ((kk * 4 + quad) ^ (l16 & 7)) * 8;
            short8 a[2];
#pragma unroll
            for (int kb = 0; kb < 2; ++kb)
                a[kb] = *(const short8*)&sK[(32 * w + kb * 16 + l16) * 128 + sc];
            short8 b[8];
#pragma unroll
            for (int qt = 0; qt < 8; ++qt)
                b[qt] = *(const short8*)&sQ[(qt * 16 + l16) * 128 + sc];
#pragma unroll
            for (int kb = 0; kb < 2; ++kb)
#pragma unroll
                for (int qt = 0; qt < 8; ++qt)
                    acc[kb][qt] = __builtin_amdgcn_mfma_f32_16x16x32_bf16(a[kb], b[qt], acc[kb][qt], 0, 0, 0);
        }
        // exp + rowsum; C row = k = 4*quad + r (+32w+16kb), col = q = l16+16qt
#pragma unroll
        for (int kb = 0; kb < 2; ++kb) {
            const int kg = k0 + 32 * w + 16 * kb + 4 * quad;
#pragma unroll
            for (int qt = 0; qt < 8; ++qt) {
                const int qg = q0 + qt * 16 + l16;
                uint2 m2 = *(const uint2*)&mbf[(size_t)qg * S_LEN + kg];
                float m0 = bf2f((unsigned short)(m2.x & 0xFFFF));
                float m1 = bf2f((unsigned short)(m2.x >> 16));
                float m2f = bf2f((unsigned short)(m2.y & 0xFFFF));
                float m3 = bf2f((unsigned short)(m2.y >> 16));
                rs[qt] += __expf(acc[kb][qt][0] + m0) + __expf(acc[kb][qt][1] + m1)
                        + __expf(acc[kb][qt][2] + m2f) + __expf(acc[kb][qt][3] + m3);
            }
        }
    }
    // reduce over quads (same q across quad groups), then across waves via LDS
#pragma unroll
    for (int qt = 0; qt < 8; ++qt) {
        float v = rs[qt];
        v += __shfl_xor(v, 16);
        v += __shfl_xor(v, 32);
        if (lane < 16) sRSp[w][qt * 16 + lane] = v;
    }
    __syncthreads();
    if (t < 128) {
        float tot = sRSp[0][t] + sRSp[1][t] + sRSp[2][t] + sRSp[3][t];
        sRL[t] = 1.0f / tot;
    }
    __syncthreads();

    // x3s[:, q0:q0+128] = bf16(x3 * rl)
    const float* x3b = x3 + (size_t)bh * (size_t)D_LEN * S_LEN;
    unsigned short* x3sp = x3s + (size_t)bh * (size_t)D_LEN * S_LEN;
#pragma unroll
    for (int i = 0; i < 16; ++i) {
        int e = (i * 256 + t) * 4;
        int r = e >> 7, c = e & 127;
        float4 v = *(const float4*)&x3b[(size_t)r * S_LEN + q0 + c];
        v.x *= sRL[c]; v.y *= sRL[c + 1]; v.z *= sRL[c + 2]; v.w *= sRL[c + 3];
        *(uint2*)&x3sp[(size_t)r * S_LEN + q0 + c] = pack4bf(v);
    }
}

// ---------- Kernel 2: out = x3s @ exp(QK + mask), 128-k blocks ----------
// grid(16, 32): x = 128-col k block, y = bh. 4 waves.
// QK: wave w owns q rows [16w,16w+16) x 128k. PV: wave w owns d [32w,32w+32).
__global__ __launch_bounds__(256, 2) void k_out(
    const unsigned short* __restrict__ x1s,
    const unsigned short* __restrict__ x2b,
    const unsigned short* __restrict__ x3s,
    const unsigned short* __restrict__ mbf,
    float* __restrict__ out)
{
    __shared__ unsigned short sK[128 * 128];  // x2 k-block (resident, swizzled)
    __shared__ unsigned short sQ[64 * 128];   // x1 q-tile (swizzled)
    __shared__ unsigned short sX[128 * 64];   // x3s tile d x q (swizzled)
    __shared__ unsigned short sE[128 * 64];   // E^T k x q (swizzled)
    const int kb0 = blockIdx.x * 128;
    const int bh = blockIdx.y;
    const unsigned short* x1p = x1s + (size_t)bh * S_LEN * D_LEN;
    const unsigned short* x2p = x2b + (size_t)bh * S_LEN * D_LEN;
    const unsigned short* x3p = x3s + (size_t)bh * (size_t)D_LEN * S_LEN;
    const int t = threadIdx.x;
    const int w = t >> 6, lane = t & 63, quad = lane >> 4, l16 = lane & 15;

#pragma unroll
    for (int i = 0; i < 8; ++i) {  // stage resident sK (128x128), swizzled
        int idx = i * 256 + t;
        int r = idx >> 4, c = idx & 15;
        *(uint4*)&sK[r * 128 + ((c ^ (r & 7)) * 8)] =
            *(const uint4*)&x2p[(size_t)(kb0 + r) * D_LEN + c * 8];
    }

    f32x4 oa[16];  // db(2) x kb(8)
#pragma unroll
    for (int i = 0; i < 16; ++i) oa[i] = (f32x4){0.f, 0.f, 0.f, 0.f};

    for (int q0 = 0; q0 < S_LEN; q0 += 64) {
        __syncthreads();
#pragma unroll
        for (int i = 0; i < 4; ++i) {  // stage sQ (64x128), swizzled
            int idx = i * 256 + t;
            int r = idx >> 4, c = idx & 15;
            *(uint4*)&sQ[r * 128 + ((c ^ (r & 7)) * 8)] =
                *(const uint4*)&x1p[(size_t)(q0 + r) * D_LEN + c * 8];
        }
#pragma unroll
        for (int i = 0; i < 4; ++i) {  // stage sX (128d x 64q), swizzled
            int idx = i * 256 + t;
            int r = idx >> 3, c = idx & 7;
            *(uint4*)&sX[r * 64 + ((c ^ (r & 7)) * 8)] =
                *(const uint4*)&x3p[(size_t)r * S_LEN + q0 + c * 8];
        }
        __syncthreads();

        // QK: 16q x 128k per wave
        f32x4 acc[8];
#pragma unroll
        for (int kb = 0; kb < 8; ++kb) acc[kb] = (f32x4){0.f, 0.f, 0.f, 0.f};
#pragma unroll
        for (int kk = 0; kk < 4; ++kk) {
            const int sc = ((kk * 4 + quad) ^ (l16 & 7)) * 8;
            short8 a = *(const short8*)&sQ[(16 * w + l16) * 128 + sc];
            short8 b[8];
#pragma unroll
            for (int kb = 0; kb < 8; ++kb)
                b[kb] = *(const short8*)&sK[(kb * 16 + l16) * 128 + sc];
#pragma unroll
            for (int kb = 0; kb < 8; ++kb)
                acc[kb] = __builtin_amdgcn_mfma_f32_16x16x32_bf16(a, b[kb], acc[kb], 0, 0, 0);
        }
        // exp + sE^T store; C row = q = 16w+4quad+r, col = k = kb*16+l16
        const int qrow = 16 * w + 4 * quad;
        const int qoff7 = (16 * w + 4 * quad) & 7;          // 8B offset in chunk
        const int cE = (16 * w + 4 * quad) >> 3;            // q chunk idx
#pragma unroll
        for (int kb = 0; kb < 8; ++kb) {
            const int kg = kb0 + kb * 16 + l16;
            unsigned short e4[4];
#pragma unroll
            for (int r = 0; r < 4; ++r) {
                float m = bf2f(mbf[(size_t)(q0 + qrow + r) * S_LEN + kg]);
                e4[r] = f2bf(__expf(acc[kb][r] + m));
            }
            uint2 pk;
            pk.x = (unsigned)e4[0] | ((unsigned)e4[1] << 16);
            pk.y = (unsigned)e4[2] | ((unsigned)e4[3] << 16);
            const int krow = kb * 16 + l16;
            *(uint2*)&sE[krow * 64 + ((cE ^ (krow & 7)) * 8) + qoff7] = pk;
        }
        __syncthreads();

        // PV: 32d x 128k per wave
#pragma unroll
        for (int kk = 0; kk < 2; ++kk) {
            const int sc = ((kk * 4 + quad) ^ (l16 & 7)) * 8;
            short8 a[2];
#pragma unroll
            for (int db = 0; db < 2; ++db)
                a[db] = *(const short8*)&sX[(32 * w + 16 * db + l16) * 64 + sc];
            short8 b[8];
#pragma unroll
            for (int kb = 0; kb < 8; ++kb)
                b[kb] = *(const short8*)&sE[(kb * 16 + l16) * 64 + sc];
#pragma unroll
            for (int db = 0; db < 2; ++db)
#pragma unroll
                for (int kb = 0; kb < 8; ++kb)
                    oa[db * 8 + kb] = __builtin_amdgcn_mfma_f32_16x16x32_bf16(a[db], b[kb], oa[db * 8 + kb], 0, 0, 0);
        }
    }

#pragma unroll
    for (int db = 0; db < 2; ++db)
#pragma unroll
        for (int kb = 0; kb < 8; ++kb)
#pragma unroll
            for (int r = 0; r < 4; ++r) {
                int d = 32 * w + 16 * db + 4 * quad + r;
                out[((size_t)bh * D_LEN + d) * S_LEN + kb0 + kb * 16 + l16] =
                    oa[db * 8 + kb][r];
            }
}

// ================= Fallback path (ws too small) =================
__global__ __launch_bounds__(256, 3) void k_rowsum_fb(
    const float* __restrict__ x1, const float* __restrict__ x2,
    const float* __restrict__ mask, float* __restrict__ rl)
{
    __shared__ unsigned short sQ[128 * 136];
    __shared__ unsigned short sK[64 * 136];
    const int q0 = blockIdx.x * 128;
    const int bh = blockIdx.y;
    const float* x1b = x1 + (size_t)bh * S_LEN * D_LEN;
    const float* x2b = x2 + (size_t)bh * S_LEN * D_LEN;
    const int t = threadIdx.x;
    const int w = t >> 6, lane = t & 63, quad = lane >> 4, l16 = lane & 15;
#pragma unroll
    for (int i = 0; i < 16; ++i) {
        int e = (i * 256 + t) * 4;
        int r = e >> 7, c = e & 127;
        float4 v = *(const float4*)&x1b[(size_t)(q0 + r) * D_LEN + c];
        *(uint2*)&sQ[r * 136 + c] = pack4bf(v);
    }
    float rs[8] = {0.f, 0.f, 0.f, 0.f, 0.f, 0.f, 0.f, 0.f};
    for (int k0 = 0; k0 < S_LEN; k0 += 64) {
        __syncthreads();
#pragma unroll
        for (int i = 0; i < 8; ++i) {
            int e = (i * 256 + t) * 4;
            int r = e >> 7, c = e & 127;
            float4 v = *(const float4*)&x2b[(size_t)(k0 + r) * D_LEN + c];
            *(uint2*)&sK[r * 136 + c] = pack4bf(v);
        }
        __syncthreads();
#pragma unroll
        for (int qb = 0; qb < 2; ++qb) {
            const int qrow = 32 * w + 16 * qb;
#pragma unroll
            for (int kb = 0; kb < 4; ++kb) {
                f32x4 acc = {0.f, 0.f, 0.f, 0.f};
#pragma unroll
                for (int kk = 0; kk < 4; ++kk) {
                    short8 a = *(const short8*)&sQ[(qrow + l16) * 136 + kk * 32 + quad * 8];
                    short8 b = *(const short8*)&sK[(kb * 16 + l16) * 136 + kk * 32 + quad * 8];
                    acc = __builtin_amdgcn_mfma_f32_16x16x32_bf16(a, b, acc, 0, 0, 0);
                }
                const int kg = k0 + kb * 16 + l16;
                const int qg = q0 + qrow + 4 * quad;
#pragma unroll
                for (int r = 0; r < 4; ++r) {
                    float m = mask[(size_t)(qg + r) * S_LEN + kg];
                    rs[qb * 4 + r] += __expf(acc[r] * SCALE_QK + m);
                }
            }
        }
    }
#pragma unroll
    for (int i = 0; i < 8; ++i) {
        float v = rs[i];
        v += __shfl_xor(v, 1); v += __shfl_xor(v, 2);
        v += __shfl_xor(v, 4); v += __shfl_xor(v, 8);
        if (l16 == 0) {
            int qg = q0 + 32 * w + 16 * (i >> 2) + 4 * quad + (i & 3);
            rl[(size_t)bh * S_LEN + qg] = 1.0f / v;
        }
    }
}

__global__ __launch_bounds__(256, 2) void k_out_fb(
    const float* __restrict__ x1, const float* __restrict__ x2,
    const float* __restrict__ x3, const float* __restrict__ mask,
    const float* __restrict__ rl, float* __restrict__ out)
{
    __shared__ unsigned short sK[64 * 136];
    __shared__ unsigned short sQ[64 * 136];
    __shared__ unsigned short sX[128 * 72];
    __shared__ unsigned short sE[64 * 72];
    const int kb0 = blockIdx.x * 64;
    const int bh = blockIdx.y;
    const float* x1b = x1 + (size_t)bh * S_LEN * D_LEN;
    const float* x2b = x2 + (size_t)bh * S_LEN * D_LEN;
    const float* x3b = x3 + (size_t)bh * (size_t)D_LEN * S_LEN;
    const float* rlb = rl + (size_t)bh * S_LEN;
    const int t = threadIdx.x;
    const int w = t >> 6, lane = t & 63, quad = lane >> 4, l16 = lane & 15;
#pragma unroll
    for (int i = 0; i < 8; ++i) {
        int e = (i * 256 + t) * 4;
        int r = e >> 7, c = e & 127;
        float4 v = *(const float4*)&x2b[(size_t)(kb0 + r) * D_LEN + c];
        *(uint2*)&sK[r * 136 + c] = pack4bf(v);
    }
    f32x4 oa[8];
#pragma unroll
    for (int i = 0; i < 8; ++i) oa[i] = (f32x4){0.f, 0.f, 0.f, 0.f};
    for (int q0 = 0; q0 < S_LEN; q0 += 64) {
        __syncthreads();
#pragma unroll
        for (int i = 0; i < 8; ++i) {
            int e = (i * 256 + t) * 4;
            int r = e >> 7, c = e & 127;
            float4 v = *(const float4*)&x1b[(size_t)(q0 + r) * D_LEN + c];
            *(uint2*)&sQ[r * 136 + c] = pack4bf(v);
        }
#pragma unroll
        for (int i = 0; i < 8; ++i) {
            int e = (i * 256 + t) * 4;
            int r = e >> 6, c = e & 63;
            float4 v = *(const float4*)&x3b[(size_t)r * S_LEN + q0 + c];
            *(uint2*)&sX[r * 72 + c] = pack4bf(v);
        }
        __syncthreads();
        const int qrow = 16 * w + 4 * quad;
        float rl4[4];
#pragma unroll
        for (int r = 0; r < 4; ++r) rl4[r] = rlb[q0 + qrow + r];
#pragma unroll
        for (int kb = 0; kb < 4; ++kb) {
            f32x4 acc = {0.f, 0.f, 0.f, 0.f};
#pragma unroll
            for (int kk = 0; kk < 4; ++kk) {
                short8 a = *(const short8*)&sQ[(16 * w + l16) * 136 + kk * 32 + quad * 8];
                short8 b = *(const short8*)&sK[(kb * 16 + l16) * 136 + kk * 32 + quad * 8];
                acc = __builtin_amdgcn_mfma_f32_16x16x32_bf16(a, b, acc, 0, 0, 0);
            }
            const int kg = kb0 + kb * 16 + l16;
            unsigned short e4[4];
#pragma unroll
            for (int r = 0; r < 4; ++r) {
                float m = mask[(size_t)(q0 + qrow + r) * S_LEN + kg];
                e4[r] = f2bf(__expf(acc[r] * SCALE_QK + m) * rl4[r]);
            }
            uint2 pk;
            pk.x = (unsigned)e4[0] | ((unsigned)e4[1] << 16);
            pk.y = (unsigned)e4[2] | ((unsigned)e4[3] << 16);
            *(uint2*)&sE[(kb * 16 + l16) * 72 + qrow] = pk;
        }
        __syncthreads();
#pragma unroll
        for (int db = 0; db < 2; ++db)
#pragma unroll
            for (int kb = 0; kb < 4; ++kb) {
                f32x4 a0 = oa[db * 4 + kb];
#pragma unroll
                for (int kk = 0; kk < 2; ++kk) {
                    short8 a = *(const short8*)&sX[(32 * w + 16 * db + l16) * 72 + kk * 32 + quad * 8];
                    short8 b = *(const short8*)&sE[(kb * 16 + l16) * 72 + kk * 32 + quad * 8];
                    a0 = __builtin_amdgcn_mfma_f32_16x16x32_bf16(a, b, a0, 0, 0, 0);
                }
                oa[db * 4 + kb] = a0;
            }
    }
#pragma unroll
    for (int db = 0; db < 2; ++db)
#pragma unroll
        for (int kb = 0; kb < 4; ++kb)
#pragma unroll
            for (int r = 0; r < 4; ++r) {
                int d = 32 * w + 16 * db + 4 * quad + r;
                out[((size_t)bh * D_LEN + d) * S_LEN + kb0 + kb * 16 + l16] =
                    oa[db * 4 + kb][r];
            }
}

extern "C" void kernel_launch(void* const* d_in, const int* in_sizes, int n_in,
                              void* d_out, int out_size, void* d_ws, size_t ws_size,
                              hipStream_t stream) {
    const float* x1 = (const float*)d_in[0];
    const float* x2 = (const float*)d_in[1];
    const float* x3 = (const float*)d_in[2];
    const float* mask = (const float*)d_in[3];
    float* out = (float*)d_out;

    const size_t N1 = (size_t)BH_N * S_LEN * D_LEN;
    const size_t NM = (size_t)S_LEN * S_LEN;
    const size_t need = (3 * N1 + NM) * sizeof(unsigned short);  // 58.7 MB

    if (ws_size >= need) {
        unsigned short* x1s = (unsigned short*)d_ws;
        unsigned short* x2b = x1s + N1;
        unsigned short* x3s = x2b + N1;
        unsigned short* mbf = x3s + N1;
        const size_t tot4 = (2 * N1 + NM) / 4;
        k_cvt<<<dim3((unsigned)(tot4 / 256)), dim3(256), 0, stream>>>(x1, x2, mask, x1s, x2b, mbf);
        k_qk<<<dim3(S_LEN / 128, BH_N), dim3(256), 0, stream>>>(x1s, x2b, mbf, x3, x3s);
        k_out<<<dim3(S_LEN / 128, BH_N), dim3(256), 0, stream>>>(x1s, x2b, x3s, mbf, out);
    } else {
        float* rl = (float*)d_ws;
        k_rowsum_fb<<<dim3(S_LEN / 128, BH_N), dim3(256), 0, stream>>>(x1, x2, mask, rl);
        k_out_fb<<<dim3(S_LEN / 64, BH_N), dim3(256), 0, stream>>>(x1, x2, x3, mask, rl, out);
    }
}